// Round 11
// baseline (164.692 us; speedup 1.0000x reference)
//
#include <hip/hip_runtime.h>
#include <math.h>

typedef unsigned short u16;
typedef unsigned int u32;
typedef __attribute__((ext_vector_type(8))) short bf16x8;
typedef __attribute__((ext_vector_type(4))) float f32x4;

#define AS1 __attribute__((address_space(1)))
#define AS3 __attribute__((address_space(3)))

static __device__ __forceinline__ u16 f2b(float f) {
  u32 u = __float_as_uint(f);
  return (u16)((u + 0x7FFFu + ((u >> 16) & 1u)) >> 16);
}
static __device__ __forceinline__ u16 f2b_fast(float f) {   // round-half-up
  return (u16)((__float_as_uint(f) + 0x8000u) >> 16);
}
static __device__ __forceinline__ float b2f(u16 b) {
  return __uint_as_float(((u32)b) << 16);
}

// ---------------------------------------------------------------------------
// prep: cast x (4096x1024) -> bf16; P (2048x64) -> bf16 (+ guard row 2048);
//       W (1024x3072) -> Wt bf16 TRANSPOSED [3072][1024] via LDS tiles.
// ---------------------------------------------------------------------------
__global__ __launch_bounds__(256) void prep(
    const float* __restrict__ x, const float* __restrict__ W,
    const float* __restrict__ P,
    u16* __restrict__ xb, u16* __restrict__ Wt, u16* __restrict__ Pb)
{
  __shared__ u16 sT[64 * 68];
  const int bid = blockIdx.x, t = threadIdx.x;
  if (bid < 4096) {
    const size_t base = (size_t)bid * 1024 + t * 4;
    const float4 v = *(const float4*)(x + base);
    const u32 lo = (u32)f2b(v.x) | ((u32)f2b(v.y) << 16);
    const u32 hi = (u32)f2b(v.z) | ((u32)f2b(v.w) << 16);
    *(uint2*)(xb + base) = make_uint2(lo, hi);
  } else if (bid < 4224) {
    const size_t base = (size_t)(bid - 4096) * 1024 + t * 4;
    const float4 v = *(const float4*)(P + base);
    const u32 lo = (u32)f2b(v.x) | ((u32)f2b(v.y) << 16);
    const u32 hi = (u32)f2b(v.z) | ((u32)f2b(v.w) << 16);
    *(uint2*)(Pb + base) = make_uint2(lo, hi);
  } else if (bid < 4992) {
    const int tb = bid - 4224;
    const int tk = tb / 48, tn = tb % 48;
    const int k0 = tk * 64, n0 = tn * 64;
#pragma unroll
    for (int it = 0; it < 4; ++it) {
      const int c = it * 256 + t;
      const int r = c >> 4, c4 = (c & 15) << 2;
      const float4 v = *(const float4*)(W + (size_t)(k0 + r) * 3072 + n0 + c4);
      sT[(c4 + 0) * 68 + r] = f2b(v.x);
      sT[(c4 + 1) * 68 + r] = f2b(v.y);
      sT[(c4 + 2) * 68 + r] = f2b(v.z);
      sT[(c4 + 3) * 68 + r] = f2b(v.w);
    }
    __syncthreads();
#pragma unroll
    for (int it = 0; it < 4; ++it) {
      const int c = it * 256 + t;
      const int rr = c >> 4, k4 = (c & 15) << 2;
      const uint2 rv = *(const uint2*)(sT + rr * 68 + k4);
      *(uint2*)(Wt + (size_t)(n0 + rr) * 1024 + k0 + k4) = rv;
    }
  } else {
    if (t < 64) Pb[2048 * 64 + t] = f2b(P[2047 * 64 + t]);  // guard row
  }
}

// ---------------------------------------------------------------------------
// qkv_gemm (bf16 MFMA): C = xb(4096x1024) @ Wt^T(1024x3072) + bias.
// THIS ROUND: counted-vmcnt pipeline (T4). The round-10 __syncthreads drained
// vmcnt(0) -> the just-issued prefetch (one ~300cy compute phase old, < L2
// latency) was waited on EVERY iter. Now: TRIPLE-buffered BK=32 staging with
// raw s_barrier + s_waitcnt vmcnt(4): prefetch k+1 stays in flight across
// the barrier; only the 4 one-iter-old loads are drained. Race-free buffer
// rotation: write target buf[(k+1)%3] was last read at iter k-2 and the
// k-1 barrier (preceded by lgkmcnt(0)) ordered those reads before this
// issue. Each wave waits its OWN vmcnt(4) before the barrier, so the
// barrier certifies all k-data is resident. LDS 48KB staging (3x8KB x2),
// epilogue tile aliases inside -> 3 blocks/CU preserved.
// Swizzle (round-10, carried): key(m) = (m&3)^((m>>2)&1); LDS[m][c] holds
// global chunk c^key(m); read chunk ql^key(m).
// ---------------------------------------------------------------------------
__global__ __launch_bounds__(256, 3) void qkv_gemm(
    const u16* __restrict__ xb, const u16* __restrict__ Wt,
    const float* __restrict__ bq,
    u16* __restrict__ Qh, u16* __restrict__ Kh, u16* __restrict__ Vt)
{
  __shared__ u16 smem[24576];        // 49152 B
  u16* const sA = smem;              // [3][128][32] staging (3 x 4096 u16)
  u16* const sB = smem + 12288;      // [3][128][32]
  u16* const T  = smem;              // epilogue [128][136] (Q/K row-major)
  u16* const Tv = smem;              // epilogue [128][136] (V: [d][q])
  const int t = threadIdx.x;
  const int lane = t & 63, w = t >> 6;
  const int l = lane & 15, ql = lane >> 4;
  const int wm = w & 1, wn = w >> 1;
  const int srow = lane >> 2;        // staging: 0..15 (4 lanes per 64B row)
  const int sc   = lane & 3;         // staging: 16B chunk within row
  const int vid = blockIdx.x;
  const int xcd = vid & 7, jj = vid >> 3;          // jj in [0,96)
  const int n0 = (xcd * 3 + (jj % 3)) * 128;
  const int m0 = (jj / 3) * 128;

  f32x4 acc[4][4];
#pragma unroll
  for (int i = 0; i < 4; ++i)
#pragma unroll
    for (int j = 0; j < 4; ++j) acc[i][j] = (f32x4){0.f, 0.f, 0.f, 0.f};

  // prologue: stage K-step 0 into buffer 0 (4 loads/wave outstanding)
#pragma unroll
  for (int j = 0; j < 2; ++j) {
    const int ii = w * 2 + j;                   // 0..7 (16 rows each)
    const int m = ii * 16 + srow;               // tile row 0..127
    const int cs = sc ^ ((m & 3) ^ ((m >> 2) & 1));
    __builtin_amdgcn_global_load_lds(
        (const AS1 u32*)(xb + (size_t)(m0 + m) * 1024 + cs * 8),
        (AS3 u32*)(sA + ii * 512), 16, 0, 0);
    __builtin_amdgcn_global_load_lds(
        (const AS1 u32*)(Wt + (size_t)(n0 + m) * 1024 + cs * 8),
        (AS3 u32*)(sB + ii * 512), 16, 0, 0);
  }

  for (int it = 0; it < 32; ++it) {
    const int cur = it % 3;

    if (it < 31) {     // prefetch K-step it+1 into buf[(it+1)%3]
      const int nb = (it + 1) % 3;
      const int kn = (it + 1) * 32;
#pragma unroll
      for (int j = 0; j < 2; ++j) {
        const int ii = w * 2 + j;
        const int m = ii * 16 + srow;
        const int cs = sc ^ ((m & 3) ^ ((m >> 2) & 1));
        __builtin_amdgcn_global_load_lds(
            (const AS1 u32*)(xb + (size_t)(m0 + m) * 1024 + kn + cs * 8),
            (AS3 u32*)(sA + nb * 4096 + ii * 512), 16, 0, 0);
        __builtin_amdgcn_global_load_lds(
            (const AS1 u32*)(Wt + (size_t)(n0 + m) * 1024 + kn + cs * 8),
            (AS3 u32*)(sB + nb * 4096 + ii * 512), 16, 0, 0);
      }
    }
    __builtin_amdgcn_sched_barrier(0);
    // own it-loads (issued last iter) done; it+1's 4 stay in flight
    if (it < 31)
      asm volatile("s_waitcnt vmcnt(4)" ::: "memory");
    else
      asm volatile("s_waitcnt vmcnt(0)" ::: "memory");
    asm volatile("s_waitcnt lgkmcnt(0)" ::: "memory");  // own prev ds_reads
    __builtin_amdgcn_s_barrier();    // all waves' it-data resident
    __builtin_amdgcn_sched_barrier(0);

    const u16* const cA = sA + cur * 4096;
    const u16* const cB = sB + cur * 4096;
    bf16x8 a[4], b[4];
#pragma unroll
    for (int mt = 0; mt < 4; ++mt) {
      const int m = wm * 64 + mt * 16 + l;
      a[mt] = *(const bf16x8*)(cA + m * 32 +
                               ((ql ^ ((m & 3) ^ ((m >> 2) & 1))) * 8));
    }
#pragma unroll
    for (int nt = 0; nt < 4; ++nt) {
      const int nn = wn * 64 + nt * 16 + l;
      b[nt] = *(const bf16x8*)(cB + nn * 32 +
                               ((ql ^ ((nn & 3) ^ ((nn >> 2) & 1))) * 8));
    }
    __builtin_amdgcn_s_setprio(1);
#pragma unroll
    for (int mt = 0; mt < 4; ++mt)
#pragma unroll
      for (int nt = 0; nt < 4; ++nt)
        acc[mt][nt] = __builtin_amdgcn_mfma_f32_16x16x32_bf16(
            a[mt], b[nt], acc[mt][nt], 0, 0, 0);
    __builtin_amdgcn_s_setprio(0);
  }

  const int which = n0 >> 10;                 // 0=Q 1=K 2=V (uniform per block)
  const int qbase = m0 & 1023;
  const int bb = m0 >> 10;
  const int h0 = (n0 & 1023) >> 6;
  __syncthreads();                            // K-loop LDS reads complete
  if (which < 2) {
    // all waves write their acc quadrant: rows wm*64+..., cols wn*64+...
#pragma unroll
    for (int nt = 0; nt < 4; ++nt) {
      const int col = wn * 64 + nt * 16 + l;
      const float bias = bq[n0 + col];
#pragma unroll
      for (int mt = 0; mt < 4; ++mt)
#pragma unroll
        for (int rg = 0; rg < 4; ++rg)
          T[(wm * 64 + mt * 16 + ql * 4 + rg) * 136 + col] =
              f2b(acc[mt][nt][rg] + bias);
    }
    __syncthreads();
    u16* const dst = which ? Kh : Qh;
#pragma unroll
    for (int h = 0; h < 2; ++h) {
      const size_t bnoff = ((size_t)(bb * 16 + h0 + h)) << 16;
#pragma unroll
      for (int it = 0; it < 4; ++it) {
        const int c = it * 256 + t;
        const int r = c >> 3, d8 = (c & 7) * 8;
        const uint4 v = *(const uint4*)(T + r * 136 + h * 64 + d8);
        *(uint4*)(dst + bnoff + ((size_t)(qbase + r) << 6) + d8) = v;
      }
    }
  } else {
    // V: transposed tile Tv[d-col=128][q-row pitch 136]
#pragma unroll
    for (int nt = 0; nt < 4; ++nt) {
      const int col = wn * 64 + nt * 16 + l;
      const float bias = bq[n0 + col];
#pragma unroll
      for (int mt = 0; mt < 4; ++mt) {
        const u32 lo = (u32)f2b(acc[mt][nt][0] + bias) |
                       ((u32)f2b(acc[mt][nt][1] + bias) << 16);
        const u32 hi = (u32)f2b(acc[mt][nt][2] + bias) |
                       ((u32)f2b(acc[mt][nt][3] + bias) << 16);
        *(uint2*)(Tv + col * 136 + wm * 64 + mt * 16 + ql * 4) =
            make_uint2(lo, hi);
      }
    }
    __syncthreads();
#pragma unroll
    for (int h = 0; h < 2; ++h) {
      const size_t bnoff = ((size_t)(bb * 16 + h0 + h)) << 16;
#pragma unroll
      for (int it = 0; it < 4; ++it) {
        const int c = it * 256 + t;
        const int dr = c >> 4, q8 = (c & 15) * 8;
        const uint4 v = *(const uint4*)(Tv + (h * 64 + dr) * 136 + q8);
        *(uint4*)(Vt + bnoff + ((size_t)dr << 10) + qbase + q8) = v;
      }
    }
  }
}

// ---------------------------------------------------------------------------
// rel_attn: round-6 version verbatim (proven best, ~56us; banked). 512
// threads / 8 waves per block, 16 q-rows per wave -> 16 waves/CU. K/V
// double-buffered LDS via DMA, P in a 256-row ring (64 new rows/iter),
// prefetch for iter k+1 issued right after the single per-iter barrier
// (compute phase ~4-5Kcy >> L2 latency, so the barrier drain is cheap here),
// z1/z2 MFMA-zero-init, setprio around MFMA clusters. LDS 72KB.
// ---------------------------------------------------------------------------
__global__ __launch_bounds__(512, 4) void rel_attn(
    const u16* __restrict__ Qh, const u16* __restrict__ Kh,
    const u16* __restrict__ Vt, const u16* __restrict__ Pb,
    const float* __restrict__ rrb, const float* __restrict__ rwb,
    float* __restrict__ out)
{
  __shared__ u16 smem[36864];        // 73728 B
  u16* const sK    = smem;           // [2][64][64] swizzled, double-buffered
  u16* const sVT   = smem + 8192;    // [2][64][64] swizzled (rows=d, cols=j)
  u16* const sPr   = smem + 16384;   // [256][64]   P ring, 64-row quadrants
  u16* const sProb = smem + 32768;   // [128][32]   swizzled half-tile
  u16* const sU    = smem;           // transient alias [128][64]
  u16* const sW    = smem + 16384;   // transient alias [128][64]

  const int t = threadIdx.x;
  const int lane = t & 63, w = t >> 6;             // w in [0,8)
  const int l = lane & 15, ql = lane >> 4;
  const int vid = blockIdx.x;
  const int qt = vid >> 6, bn = vid & 63;          // vid&7 == bn&7 (XCD)
  const int n = bn & 15, bb = bn >> 4;
  const size_t hoff = (size_t)bn << 16;
  const int q0 = qt << 7;
  const int bz = 7 - w;                            // z2 rel-tile base (5 tiles)

  // stage U = Q+rr, W = Q+rw+K (128 query rows), swizzled pitch-64
#pragma unroll
  for (int it = 0; it < 2; ++it) {
    const int c = it * 512 + t;
    const int i = c >> 3, ch = c & 7;
    const int d8 = ch * 8;
    const uint4 qv = *(const uint4*)(Qh + hoff + ((size_t)(q0 + i) << 6) + d8);
    const uint4 kv = *(const uint4*)(Kh + hoff + ((size_t)(q0 + i) << 6) + d8);
    const u16* qp = (const u16*)&qv;
    const u16* kp = (const u16*)&kv;
    u16 uo[8], wo[8];
#pragma unroll
    for (int e = 0; e < 8; ++e) {
      const float rv = rrb[n * 64 + d8 + e];
      const float wv = rwb[n * 64 + d8 + e];
      const float qf = b2f(qp[e]), kf = b2f(kp[e]);
      uo[e] = f2b(qf + rv);
      wo[e] = f2b(qf + wv + kf);
    }
    const int pos = i * 64 + ((ch ^ (i & 7)) * 8);
    *(uint4*)(sU + pos) = *(const uint4*)uo;
    *(uint4*)(sW + pos) = *(const uint4*)wo;
  }
  __syncthreads();

  bf16x8 au[2], aw[2];               // [ks], loop-invariant A-frags (16 rows)
#pragma unroll
  for (int ks = 0; ks < 2; ++ks) {
    const int row = w * 16 + l;
    const int off = row * 64 + (((ks * 4 + ql) ^ (row & 7)) * 8);
    au[ks] = *(const bf16x8*)(sU + off);
    aw[ks] = *(const bf16x8*)(sW + off);
  }
  __syncthreads();   // all frag reads done before DMA overwrites sU/sW region

  // initial staging: K(0)->sK[0], V(0)->sVT[0], P rows [lbase0, lbase0+192)
  {
    const int m = w * 8 + (lane >> 3);
    const int q8 = (lane & 7) ^ (m & 7);
    __builtin_amdgcn_global_load_lds(
        (const AS1 u32*)(Kh + hoff + ((size_t)m << 6) + q8 * 8),
        (AS3 u32*)(sK + w * 512), 16, 0, 0);
    __builtin_amdgcn_global_load_lds(
        (const AS1 u32*)(Vt + hoff + ((size_t)m << 10) + q8 * 8),
        (AS3 u32*)(sVT + w * 512), 16, 0, 0);
    const int lbase0 = 897 - q0;
    const int rb0 = (896 - q0) & 255;
#pragma unroll
    for (int j = 0; j < 3; ++j) {
      const int ii = w * 3 + j;                  // 0..23 -> 192 rows
      const int mm = ii * 8 + (lane >> 3);
      const int qq = (lane & 7) ^ (mm & 7);
      __builtin_amdgcn_global_load_lds(
          (const AS1 u32*)(Pb + ((size_t)(lbase0 + mm) << 6) + qq * 8),
          (AS3 u32*)(sPr + ((rb0 + ii * 8) & 255) * 64), 16, 0, 0);
    }
  }

  const f32x4 Z0 = (f32x4){0.f, 0.f, 0.f, 0.f};
  f32x4 o[4];
  float lrun[4];
#pragma unroll
  for (int ii = 0; ii < 4; ++ii) {
    o[ii] = (f32x4){0.f, 0.f, 0.f, 0.f};
    lrun[ii] = 0.f;
  }

  for (int k0 = 0; k0 < 1024; k0 += 64) {
    const int cb = (k0 >> 6) & 1;
    const int rb = (896 + k0 - q0) & 255;     // ring quadrant base (lbase-1)
    __syncthreads();   // drains own vmcnt -> this iter's tiles are resident

    if (k0 < 960) {    // prefetch iter k+1: 3 loads/wave, issued pre-compute
      const int kn = k0 + 64;
      const int m = w * 8 + (lane >> 3);
      const int q8 = (lane & 7) ^ (m & 7);
      __builtin_amdgcn_global_load_lds(
          (const AS1 u32*)(Kh + hoff + ((size_t)(kn + m) << 6) + q8 * 8),
          (AS3 u32*)(sK + (cb ^ 1) * 4096 + w * 512), 16, 0, 0);
      __builtin_amdgcn_global_load_lds(
          (const AS1 u32*)(Vt + hoff + ((size_t)m << 10) + kn + q8 * 8),
          (AS3 u32*)(sVT + (cb ^ 1) * 4096 + w * 512), 16, 0, 0);
      // new P rows [lbase+192, lbase+256) -> ring quadrant (rb+192)
      __builtin_amdgcn_global_load_lds(
          (const AS1 u32*)(Pb + ((size_t)(897 + kn + 128 - q0 + m) << 6) + q8 * 8),
          (AS3 u32*)(sPr + ((rb + 192 + w * 8) & 255) * 64), 16, 0, 0);
    }

    const u16* const cK = sK + cb * 4096;
    const u16* const cV = sVT + cb * 4096;

    f32x4 z1[4], z2[5];
    __builtin_amdgcn_s_setprio(1);
#pragma unroll
    for (int ks = 0; ks < 2; ++ks) {
#pragma unroll
      for (int nt = 0; nt < 4; ++nt) {
        const int row = nt * 16 + l;
        const bf16x8 bk =
            *(const bf16x8*)(cK + row * 64 + (((ks * 4 + ql) ^ (row & 7)) * 8));
        z1[nt] = __builtin_amdgcn_mfma_f32_16x16x32_bf16(
            au[ks], bk, ks ? z1[nt] : Z0, 0, 0, 0);
      }
      // 5 P B-tiles from the ring: rel tiles bz..bz+4 (bz = 7-w)
#pragma unroll
      for (int rt = 0; rt < 5; ++rt) {
        const int row = (bz + rt) * 16 + l;
        const bf16x8 bp = *(const bf16x8*)(
            sPr + ((rb + row) & 255) * 64 + (((ks * 4 + ql) ^ (row & 7)) * 8));
        z2[rt] = __builtin_amdgcn_mfma_f32_16x16x32_bf16(
            aw[ks], bp, ks ? z2[rt] : Z0, 0, 0, 0);
      }
    }
    __builtin_amdgcn_s_setprio(0);

    // diagonal gather + exp2 (rows i = 16w + 4ql + ii)
    float p[4][4];
#pragma unroll
    for (int ii = 0; ii < 4; ++ii) {
      const int ci = 15 - ql * 4 - ii;               // c' & 15
      const int src = (lane & 48) | ((l + ci) & 15);
      const bool wrap = l < ci;
#pragma unroll
      for (int jt = 0; jt < 4; ++jt) {
        const float val = wrap ? z2[jt + 1][ii] : z2[jt][ii];
        const float g = __shfl(val, src, 64);
        const float pv =
            __builtin_amdgcn_exp2f((z1[jt][ii] + g) * 0.18033688011112042f);
        p[ii][jt] = pv;
        lrun[ii] += pv;
      }
    }

    // PV in two K=32 steps through the 16-row wave-private prob stripe
#pragma unroll
    for (int ks = 0; ks < 2; ++ks) {
#pragma unroll
      for (int ii = 0; ii < 4; ++ii) {
        const int r = w * 16 + ql * 4 + ii;
        const int sw2 = (r & 3) ^ ((r >> 2) & 3);
#pragma unroll
        for (int jh = 0; jh < 2; ++jh) {
          const int ch = jh * 2 + (l >> 3);
          sProb[r * 32 + ((ch ^ sw2) * 8) + (l & 7)] =
              f2b_fast(p[ii][ks * 2 + jh]);
        }
      }
      bf16x8 bv[4];
#pragma unroll
      for (int dt = 0; dt < 4; ++dt) {
        const int row = dt * 16 + l;
        bv[dt] =
            *(const bf16x8*)(cV + row * 64 + (((ks * 4 + ql) ^ (row & 7)) * 8));
      }
      __builtin_amdgcn_s_setprio(1);
      {
        const int ar = w * 16 + l;
        const bf16x8 ap = *(const bf16x8*)(
            sProb + ar * 32 + ((ql ^ ((ar & 3) ^ ((ar >> 2) & 3))) * 8));
#pragma unroll
        for (int dt = 0; dt < 4; ++dt)
          o[dt] = __builtin_amdgcn_mfma_f32_16x16x32_bf16(
              ap, bv[dt], o[dt], 0, 0, 0);
      }
      __builtin_amdgcn_s_setprio(0);
    }
  }

  // epilogue: row-sum reduce, normalize, store fp32 (B, L, D)
#pragma unroll
  for (int ii = 0; ii < 4; ++ii) {
    float ls = lrun[ii];
    ls += __shfl_xor(ls, 1);
    ls += __shfl_xor(ls, 2);
    ls += __shfl_xor(ls, 4);
    ls += __shfl_xor(ls, 8);
    const float inv = 1.f / ls;
    const int q = q0 + w * 16 + ql * 4 + ii;
#pragma unroll
    for (int dt = 0; dt < 4; ++dt)
      out[((size_t)(bb * 1024 + q) << 10) + (n << 6) + dt * 16 + l] =
          o[dt][ii] * inv;
  }
}

// ---------------------------------------------------------------------------
extern "C" void kernel_launch(void* const* d_in, const int* in_sizes, int n_in,
                              void* d_out, int out_size, void* d_ws, size_t ws_size,
                              hipStream_t stream) {
  const float* x  = (const float*)d_in[0];  // (4,1024,1024)
  const float* P  = (const float*)d_in[1];  // (2048,64)
  const float* Wq = (const float*)d_in[2];  // (1024,3072)
  const float* bq = (const float*)d_in[3];  // (3072,)
  const float* rr = (const float*)d_in[4];  // (16,64)
  const float* rw = (const float*)d_in[5];  // (16,64)
  float* out = (float*)d_out;

  char* ws = (char*)d_ws;
  u16* xb = (u16*)(ws);                      // 8 MB
  u16* Wt = (u16*)(ws + 8388608);            // 6 MB  [3072][1024]
  u16* Pb = (u16*)(ws + 14680064);           // 2049 rows x 64 (+guard)
  u16* Qh = (u16*)(ws + 14946304);           // 8 MB  [bn][q][d]
  u16* Kh = (u16*)(ws + 23334912);           // 8 MB
  u16* Vt = (u16*)(ws + 31723520);           // 8 MB  [bn][d][q]

  prep<<<4993, 256, 0, stream>>>(x, Wq, P, xb, Wt, Pb);
  qkv_gemm<<<768, 256, 0, stream>>>(xb, Wt, bq, Qh, Kh, Vt);
  rel_attn<<<512, 512, 0, stream>>>(Qh, Kh, Vt, Pb, rr, rw, out);
}

// Round 12
// 162.737 us; speedup vs baseline: 1.0120x; 1.0120x over previous
//
#include <hip/hip_runtime.h>
#include <math.h>

typedef unsigned short u16;
typedef unsigned int u32;
typedef __attribute__((ext_vector_type(8))) short bf16x8;
typedef __attribute__((ext_vector_type(4))) float f32x4;

#define AS1 __attribute__((address_space(1)))
#define AS3 __attribute__((address_space(3)))

static __device__ __forceinline__ u16 f2b(float f) {
  u32 u = __float_as_uint(f);
  return (u16)((u + 0x7FFFu + ((u >> 16) & 1u)) >> 16);
}
static __device__ __forceinline__ u16 f2b_fast(float f) {   // round-half-up
  return (u16)((__float_as_uint(f) + 0x8000u) >> 16);
}
static __device__ __forceinline__ float b2f(u16 b) {
  return __uint_as_float(((u32)b) << 16);
}

// ---------------------------------------------------------------------------
// prep v2: RE-GRIDDED (913 blocks, was 4993). Old grid: 4224 blocks doing
// 4KB each -> launch-granularity bound (per-block fixed cost >> work).
// Now: x = 512 blocks x 8 row-chunks (32KB/block); P = 16 blocks x 8 chunks;
// W-transpose = 384 blocks x 2 tiles (sT reused, barrier between);
// guard row = 1 block. Same per-element instruction stream.
// ---------------------------------------------------------------------------
__global__ __launch_bounds__(256) void prep(
    const float* __restrict__ x, const float* __restrict__ W,
    const float* __restrict__ P,
    u16* __restrict__ xb, u16* __restrict__ Wt, u16* __restrict__ Pb)
{
  __shared__ u16 sT[64 * 68];
  const int bid = blockIdx.x, t = threadIdx.x;
  if (bid < 512) {
    // x: 8 chunks of 1024 floats (4096 x 1024 total)
#pragma unroll
    for (int r8 = 0; r8 < 8; ++r8) {
      const size_t base = ((size_t)bid * 8 + r8) * 1024 + t * 4;
      const float4 v = *(const float4*)(x + base);
      const u32 lo = (u32)f2b(v.x) | ((u32)f2b(v.y) << 16);
      const u32 hi = (u32)f2b(v.z) | ((u32)f2b(v.w) << 16);
      *(uint2*)(xb + base) = make_uint2(lo, hi);
    }
  } else if (bid < 528) {
    // P: 16 blocks x 8 chunks x 1024 floats (2048 x 64 total)
#pragma unroll
    for (int r8 = 0; r8 < 8; ++r8) {
      const size_t base = ((size_t)(bid - 512) * 8 + r8) * 1024 + t * 4;
      const float4 v = *(const float4*)(P + base);
      const u32 lo = (u32)f2b(v.x) | ((u32)f2b(v.y) << 16);
      const u32 hi = (u32)f2b(v.z) | ((u32)f2b(v.w) << 16);
      *(uint2*)(Pb + base) = make_uint2(lo, hi);
    }
  } else if (bid < 912) {
    // W-transpose: 2 tiles per block (768 tiles total)
#pragma unroll
    for (int half = 0; half < 2; ++half) {
      const int tb = (bid - 528) * 2 + half;
      const int tk = tb / 48, tn = tb % 48;
      const int k0 = tk * 64, n0 = tn * 64;
#pragma unroll
      for (int it = 0; it < 4; ++it) {
        const int c = it * 256 + t;
        const int r = c >> 4, c4 = (c & 15) << 2;
        const float4 v = *(const float4*)(W + (size_t)(k0 + r) * 3072 + n0 + c4);
        sT[(c4 + 0) * 68 + r] = f2b(v.x);
        sT[(c4 + 1) * 68 + r] = f2b(v.y);
        sT[(c4 + 2) * 68 + r] = f2b(v.z);
        sT[(c4 + 3) * 68 + r] = f2b(v.w);
      }
      __syncthreads();
#pragma unroll
      for (int it = 0; it < 4; ++it) {
        const int c = it * 256 + t;
        const int rr = c >> 4, k4 = (c & 15) << 2;
        const uint2 rv = *(const uint2*)(sT + rr * 68 + k4);
        *(uint2*)(Wt + (size_t)(n0 + rr) * 1024 + k0 + k4) = rv;
      }
      __syncthreads();   // guard sT reuse for second tile
    }
  } else {
    if (t < 64) Pb[2048 * 64 + t] = f2b(P[2047 * 64 + t]);  // guard row
  }
}

// ---------------------------------------------------------------------------
// qkv_gemm (bf16 MFMA): C = xb(4096x1024) @ Wt^T(1024x3072) + bias.
// Round-11 version carried: counted-vmcnt triple-buffered BK=32 pipeline
// (raw s_barrier + s_waitcnt vmcnt(4); prefetch stays in flight across the
// barrier). Swizzle: key(m) = (m&3)^((m>>2)&1). LDS 48KB staging, epilogue
// tile aliases inside -> 3 blocks/CU. Single-pass epilogue; V transposed.
// ---------------------------------------------------------------------------
__global__ __launch_bounds__(256, 3) void qkv_gemm(
    const u16* __restrict__ xb, const u16* __restrict__ Wt,
    const float* __restrict__ bq,
    u16* __restrict__ Qh, u16* __restrict__ Kh, u16* __restrict__ Vt)
{
  __shared__ u16 smem[24576];        // 49152 B
  u16* const sA = smem;              // [3][128][32] staging (3 x 4096 u16)
  u16* const sB = smem + 12288;      // [3][128][32]
  u16* const T  = smem;              // epilogue [128][136] (Q/K row-major)
  u16* const Tv = smem;              // epilogue [128][136] (V: [d][q])
  const int t = threadIdx.x;
  const int lane = t & 63, w = t >> 6;
  const int l = lane & 15, ql = lane >> 4;
  const int wm = w & 1, wn = w >> 1;
  const int srow = lane >> 2;        // staging: 0..15 (4 lanes per 64B row)
  const int sc   = lane & 3;         // staging: 16B chunk within row
  const int vid = blockIdx.x;
  const int xcd = vid & 7, jj = vid >> 3;          // jj in [0,96)
  const int n0 = (xcd * 3 + (jj % 3)) * 128;
  const int m0 = (jj / 3) * 128;

  f32x4 acc[4][4];
#pragma unroll
  for (int i = 0; i < 4; ++i)
#pragma unroll
    for (int j = 0; j < 4; ++j) acc[i][j] = (f32x4){0.f, 0.f, 0.f, 0.f};

  // prologue: stage K-step 0 into buffer 0 (4 loads/wave outstanding)
#pragma unroll
  for (int j = 0; j < 2; ++j) {
    const int ii = w * 2 + j;                   // 0..7 (16 rows each)
    const int m = ii * 16 + srow;               // tile row 0..127
    const int cs = sc ^ ((m & 3) ^ ((m >> 2) & 1));
    __builtin_amdgcn_global_load_lds(
        (const AS1 u32*)(xb + (size_t)(m0 + m) * 1024 + cs * 8),
        (AS3 u32*)(sA + ii * 512), 16, 0, 0);
    __builtin_amdgcn_global_load_lds(
        (const AS1 u32*)(Wt + (size_t)(n0 + m) * 1024 + cs * 8),
        (AS3 u32*)(sB + ii * 512), 16, 0, 0);
  }

  for (int it = 0; it < 32; ++it) {
    const int cur = it % 3;

    if (it < 31) {     // prefetch K-step it+1 into buf[(it+1)%3]
      const int nb = (it + 1) % 3;
      const int kn = (it + 1) * 32;
#pragma unroll
      for (int j = 0; j < 2; ++j) {
        const int ii = w * 2 + j;
        const int m = ii * 16 + srow;
        const int cs = sc ^ ((m & 3) ^ ((m >> 2) & 1));
        __builtin_amdgcn_global_load_lds(
            (const AS1 u32*)(xb + (size_t)(m0 + m) * 1024 + kn + cs * 8),
            (AS3 u32*)(sA + nb * 4096 + ii * 512), 16, 0, 0);
        __builtin_amdgcn_global_load_lds(
            (const AS1 u32*)(Wt + (size_t)(n0 + m) * 1024 + kn + cs * 8),
            (AS3 u32*)(sB + nb * 4096 + ii * 512), 16, 0, 0);
      }
    }
    __builtin_amdgcn_sched_barrier(0);
    // own it-loads (issued last iter) done; it+1's 4 stay in flight
    if (it < 31)
      asm volatile("s_waitcnt vmcnt(4)" ::: "memory");
    else
      asm volatile("s_waitcnt vmcnt(0)" ::: "memory");
    asm volatile("s_waitcnt lgkmcnt(0)" ::: "memory");  // own prev ds_reads
    __builtin_amdgcn_s_barrier();    // all waves' it-data resident
    __builtin_amdgcn_sched_barrier(0);

    const u16* const cA = sA + cur * 4096;
    const u16* const cB = sB + cur * 4096;
    bf16x8 a[4], b[4];
#pragma unroll
    for (int mt = 0; mt < 4; ++mt) {
      const int m = wm * 64 + mt * 16 + l;
      a[mt] = *(const bf16x8*)(cA + m * 32 +
                               ((ql ^ ((m & 3) ^ ((m >> 2) & 1))) * 8));
    }
#pragma unroll
    for (int nt = 0; nt < 4; ++nt) {
      const int nn = wn * 64 + nt * 16 + l;
      b[nt] = *(const bf16x8*)(cB + nn * 32 +
                               ((ql ^ ((nn & 3) ^ ((nn >> 2) & 1))) * 8));
    }
    __builtin_amdgcn_s_setprio(1);
#pragma unroll
    for (int mt = 0; mt < 4; ++mt)
#pragma unroll
      for (int nt = 0; nt < 4; ++nt)
        acc[mt][nt] = __builtin_amdgcn_mfma_f32_16x16x32_bf16(
            a[mt], b[nt], acc[mt][nt], 0, 0, 0);
    __builtin_amdgcn_s_setprio(0);
  }

  const int which = n0 >> 10;                 // 0=Q 1=K 2=V (uniform per block)
  const int qbase = m0 & 1023;
  const int bb = m0 >> 10;
  const int h0 = (n0 & 1023) >> 6;
  __syncthreads();                            // K-loop LDS reads complete
  if (which < 2) {
    // all waves write their acc quadrant: rows wm*64+..., cols wn*64+...
#pragma unroll
    for (int nt = 0; nt < 4; ++nt) {
      const int col = wn * 64 + nt * 16 + l;
      const float bias = bq[n0 + col];
#pragma unroll
      for (int mt = 0; mt < 4; ++mt)
#pragma unroll
        for (int rg = 0; rg < 4; ++rg)
          T[(wm * 64 + mt * 16 + ql * 4 + rg) * 136 + col] =
              f2b(acc[mt][nt][rg] + bias);
    }
    __syncthreads();
    u16* const dst = which ? Kh : Qh;
#pragma unroll
    for (int h = 0; h < 2; ++h) {
      const size_t bnoff = ((size_t)(bb * 16 + h0 + h)) << 16;
#pragma unroll
      for (int it = 0; it < 4; ++it) {
        const int c = it * 256 + t;
        const int r = c >> 3, d8 = (c & 7) * 8;
        const uint4 v = *(const uint4*)(T + r * 136 + h * 64 + d8);
        *(uint4*)(dst + bnoff + ((size_t)(qbase + r) << 6) + d8) = v;
      }
    }
  } else {
    // V: transposed tile Tv[d-col=128][q-row pitch 136]
#pragma unroll
    for (int nt = 0; nt < 4; ++nt) {
      const int col = wn * 64 + nt * 16 + l;
      const float bias = bq[n0 + col];
#pragma unroll
      for (int mt = 0; mt < 4; ++mt) {
        const u32 lo = (u32)f2b(acc[mt][nt][0] + bias) |
                       ((u32)f2b(acc[mt][nt][1] + bias) << 16);
        const u32 hi = (u32)f2b(acc[mt][nt][2] + bias) |
                       ((u32)f2b(acc[mt][nt][3] + bias) << 16);
        *(uint2*)(Tv + col * 136 + wm * 64 + mt * 16 + ql * 4) =
            make_uint2(lo, hi);
      }
    }
    __syncthreads();
#pragma unroll
    for (int h = 0; h < 2; ++h) {
      const size_t bnoff = ((size_t)(bb * 16 + h0 + h)) << 16;
#pragma unroll
      for (int it = 0; it < 4; ++it) {
        const int c = it * 256 + t;
        const int dr = c >> 4, q8 = (c & 15) * 8;
        const uint4 v = *(const uint4*)(Tv + (h * 64 + dr) * 136 + q8);
        *(uint4*)(Vt + bnoff + ((size_t)dr << 10) + qbase + q8) = v;
      }
    }
  }
}

// ---------------------------------------------------------------------------
// rel_attn: round-6 version verbatim (proven best, ~56-59us; banked). 512
// threads / 8 waves per block, 16 q-rows per wave -> 16 waves/CU. K/V
// double-buffered LDS via DMA, P in a 256-row ring (64 new rows/iter),
// prefetch for iter k+1 issued right after the single per-iter barrier
// (compute phase ~4-5Kcy >> L2 latency, so the barrier drain is cheap here),
// z1/z2 MFMA-zero-init, setprio around MFMA clusters. LDS 72KB.
// ---------------------------------------------------------------------------
__global__ __launch_bounds__(512, 4) void rel_attn(
    const u16* __restrict__ Qh, const u16* __restrict__ Kh,
    const u16* __restrict__ Vt, const u16* __restrict__ Pb,
    const float* __restrict__ rrb, const float* __restrict__ rwb,
    float* __restrict__ out)
{
  __shared__ u16 smem[36864];        // 73728 B
  u16* const sK    = smem;           // [2][64][64] swizzled, double-buffered
  u16* const sVT   = smem + 8192;    // [2][64][64] swizzled (rows=d, cols=j)
  u16* const sPr   = smem + 16384;   // [256][64]   P ring, 64-row quadrants
  u16* const sProb = smem + 32768;   // [128][32]   swizzled half-tile
  u16* const sU    = smem;           // transient alias [128][64]
  u16* const sW    = smem + 16384;   // transient alias [128][64]

  const int t = threadIdx.x;
  const int lane = t & 63, w = t >> 6;             // w in [0,8)
  const int l = lane & 15, ql = lane >> 4;
  const int vid = blockIdx.x;
  const int qt = vid >> 6, bn = vid & 63;          // vid&7 == bn&7 (XCD)
  const int n = bn & 15, bb = bn >> 4;
  const size_t hoff = (size_t)bn << 16;
  const int q0 = qt << 7;
  const int bz = 7 - w;                            // z2 rel-tile base (5 tiles)

  // stage U = Q+rr, W = Q+rw+K (128 query rows), swizzled pitch-64
#pragma unroll
  for (int it = 0; it < 2; ++it) {
    const int c = it * 512 + t;
    const int i = c >> 3, ch = c & 7;
    const int d8 = ch * 8;
    const uint4 qv = *(const uint4*)(Qh + hoff + ((size_t)(q0 + i) << 6) + d8);
    const uint4 kv = *(const uint4*)(Kh + hoff + ((size_t)(q0 + i) << 6) + d8);
    const u16* qp = (const u16*)&qv;
    const u16* kp = (const u16*)&kv;
    u16 uo[8], wo[8];
#pragma unroll
    for (int e = 0; e < 8; ++e) {
      const float rv = rrb[n * 64 + d8 + e];
      const float wv = rwb[n * 64 + d8 + e];
      const float qf = b2f(qp[e]), kf = b2f(kp[e]);
      uo[e] = f2b(qf + rv);
      wo[e] = f2b(qf + wv + kf);
    }
    const int pos = i * 64 + ((ch ^ (i & 7)) * 8);
    *(uint4*)(sU + pos) = *(const uint4*)uo;
    *(uint4*)(sW + pos) = *(const uint4*)wo;
  }
  __syncthreads();

  bf16x8 au[2], aw[2];               // [ks], loop-invariant A-frags (16 rows)
#pragma unroll
  for (int ks = 0; ks < 2; ++ks) {
    const int row = w * 16 + l;
    const int off = row * 64 + (((ks * 4 + ql) ^ (row & 7)) * 8);
    au[ks] = *(const bf16x8*)(sU + off);
    aw[ks] = *(const bf16x8*)(sW + off);
  }
  __syncthreads();   // all frag reads done before DMA overwrites sU/sW region

  // initial staging: K(0)->sK[0], V(0)->sVT[0], P rows [lbase0, lbase0+192)
  {
    const int m = w * 8 + (lane >> 3);
    const int q8 = (lane & 7) ^ (m & 7);
    __builtin_amdgcn_global_load_lds(
        (const AS1 u32*)(Kh + hoff + ((size_t)m << 6) + q8 * 8),
        (AS3 u32*)(sK + w * 512), 16, 0, 0);
    __builtin_amdgcn_global_load_lds(
        (const AS1 u32*)(Vt + hoff + ((size_t)m << 10) + q8 * 8),
        (AS3 u32*)(sVT + w * 512), 16, 0, 0);
    const int lbase0 = 897 - q0;
    const int rb0 = (896 - q0) & 255;
#pragma unroll
    for (int j = 0; j < 3; ++j) {
      const int ii = w * 3 + j;                  // 0..23 -> 192 rows
      const int mm = ii * 8 + (lane >> 3);
      const int qq = (lane & 7) ^ (mm & 7);
      __builtin_amdgcn_global_load_lds(
          (const AS1 u32*)(Pb + ((size_t)(lbase0 + mm) << 6) + qq * 8),
          (AS3 u32*)(sPr + ((rb0 + ii * 8) & 255) * 64), 16, 0, 0);
    }
  }

  const f32x4 Z0 = (f32x4){0.f, 0.f, 0.f, 0.f};
  f32x4 o[4];
  float lrun[4];
#pragma unroll
  for (int ii = 0; ii < 4; ++ii) {
    o[ii] = (f32x4){0.f, 0.f, 0.f, 0.f};
    lrun[ii] = 0.f;
  }

  for (int k0 = 0; k0 < 1024; k0 += 64) {
    const int cb = (k0 >> 6) & 1;
    const int rb = (896 + k0 - q0) & 255;     // ring quadrant base (lbase-1)
    __syncthreads();   // drains own vmcnt -> this iter's tiles are resident

    if (k0 < 960) {    // prefetch iter k+1: 3 loads/wave, issued pre-compute
      const int kn = k0 + 64;
      const int m = w * 8 + (lane >> 3);
      const int q8 = (lane & 7) ^ (m & 7);
      __builtin_amdgcn_global_load_lds(
          (const AS1 u32*)(Kh + hoff + ((size_t)(kn + m) << 6) + q8 * 8),
          (AS3 u32*)(sK + (cb ^ 1) * 4096 + w * 512), 16, 0, 0);
      __builtin_amdgcn_global_load_lds(
          (const AS1 u32*)(Vt + hoff + ((size_t)m << 10) + kn + q8 * 8),
          (AS3 u32*)(sVT + (cb ^ 1) * 4096 + w * 512), 16, 0, 0);
      // new P rows [lbase+192, lbase+256) -> ring quadrant (rb+192)
      __builtin_amdgcn_global_load_lds(
          (const AS1 u32*)(Pb + ((size_t)(897 + kn + 128 - q0 + m) << 6) + q8 * 8),
          (AS3 u32*)(sPr + ((rb + 192 + w * 8) & 255) * 64), 16, 0, 0);
    }

    const u16* const cK = sK + cb * 4096;
    const u16* const cV = sVT + cb * 4096;

    f32x4 z1[4], z2[5];
    __builtin_amdgcn_s_setprio(1);
#pragma unroll
    for (int ks = 0; ks < 2; ++ks) {
#pragma unroll
      for (int nt = 0; nt < 4; ++nt) {
        const int row = nt * 16 + l;
        const bf16x8 bk =
            *(const bf16x8*)(cK + row * 64 + (((ks * 4 + ql) ^ (row & 7)) * 8));
        z1[nt] = __builtin_amdgcn_mfma_f32_16x16x32_bf16(
            au[ks], bk, ks ? z1[nt] : Z0, 0, 0, 0);
      }
      // 5 P B-tiles from the ring: rel tiles bz..bz+4 (bz = 7-w)
#pragma unroll
      for (int rt = 0; rt < 5; ++rt) {
        const int row = (bz + rt) * 16 + l;
        const bf16x8 bp = *(const bf16x8*)(
            sPr + ((rb + row) & 255) * 64 + (((ks * 4 + ql) ^ (row & 7)) * 8));
        z2[rt] = __builtin_amdgcn_mfma_f32_16x16x32_bf16(
            aw[ks], bp, ks ? z2[rt] : Z0, 0, 0, 0);
      }
    }
    __builtin_amdgcn_s_setprio(0);

    // diagonal gather + exp2 (rows i = 16w + 4ql + ii)
    float p[4][4];
#pragma unroll
    for (int ii = 0; ii < 4; ++ii) {
      const int ci = 15 - ql * 4 - ii;               // c' & 15
      const int src = (lane & 48) | ((l + ci) & 15);
      const bool wrap = l < ci;
#pragma unroll
      for (int jt = 0; jt < 4; ++jt) {
        const float val = wrap ? z2[jt + 1][ii] : z2[jt][ii];
        const float g = __shfl(val, src, 64);
        const float pv =
            __builtin_amdgcn_exp2f((z1[jt][ii] + g) * 0.18033688011112042f);
        p[ii][jt] = pv;
        lrun[ii] += pv;
      }
    }

    // PV in two K=32 steps through the 16-row wave-private prob stripe
#pragma unroll
    for (int ks = 0; ks < 2; ++ks) {
#pragma unroll
      for (int ii = 0; ii < 4; ++ii) {
        const int r = w * 16 + ql * 4 + ii;
        const int sw2 = (r & 3) ^ ((r >> 2) & 3);
#pragma unroll
        for (int jh = 0; jh < 2; ++jh) {
          const int ch = jh * 2 + (l >> 3);
          sProb[r * 32 + ((ch ^ sw2) * 8) + (l & 7)] =
              f2b_fast(p[ii][ks * 2 + jh]);
        }
      }
      bf16x8 bv[4];
#pragma unroll
      for (int dt = 0; dt < 4; ++dt) {
        const int row = dt * 16 + l;
        bv[dt] =
            *(const bf16x8*)(cV + row * 64 + (((ks * 4 + ql) ^ (row & 7)) * 8));
      }
      __builtin_amdgcn_s_setprio(1);
      {
        const int ar = w * 16 + l;
        const bf16x8 ap = *(const bf16x8*)(
            sProb + ar * 32 + ((ql ^ ((ar & 3) ^ ((ar >> 2) & 3))) * 8));
#pragma unroll
        for (int dt = 0; dt < 4; ++dt)
          o[dt] = __builtin_amdgcn_mfma_f32_16x16x32_bf16(
              ap, bv[dt], o[dt], 0, 0, 0);
      }
      __builtin_amdgcn_s_setprio(0);
    }
  }

  // epilogue: row-sum reduce, normalize, store fp32 (B, L, D)
#pragma unroll
  for (int ii = 0; ii < 4; ++ii) {
    float ls = lrun[ii];
    ls += __shfl_xor(ls, 1);
    ls += __shfl_xor(ls, 2);
    ls += __shfl_xor(ls, 4);
    ls += __shfl_xor(ls, 8);
    const float inv = 1.f / ls;
    const int q = q0 + w * 16 + ql * 4 + ii;
#pragma unroll
    for (int dt = 0; dt < 4; ++dt)
      out[((size_t)(bb * 1024 + q) << 10) + (n << 6) + dt * 16 + l] =
          o[dt][ii] * inv;
  }
}

// ---------------------------------------------------------------------------
extern "C" void kernel_launch(void* const* d_in, const int* in_sizes, int n_in,
                              void* d_out, int out_size, void* d_ws, size_t ws_size,
                              hipStream_t stream) {
  const float* x  = (const float*)d_in[0];  // (4,1024,1024)
  const float* P  = (const float*)d_in[1];  // (2048,64)
  const float* Wq = (const float*)d_in[2];  // (1024,3072)
  const float* bq = (const float*)d_in[3];  // (3072,)
  const float* rr = (const float*)d_in[4];  // (16,64)
  const float* rw = (const float*)d_in[5];  // (16,64)
  float* out = (float*)d_out;

  char* ws = (char*)d_ws;
  u16* xb = (u16*)(ws);                      // 8 MB
  u16* Wt = (u16*)(ws + 8388608);            // 6 MB  [3072][1024]
  u16* Pb = (u16*)(ws + 14680064);           // 2049 rows x 64 (+guard)
  u16* Qh = (u16*)(ws + 14946304);           // 8 MB  [bn][q][d]
  u16* Kh = (u16*)(ws + 23334912);           // 8 MB
  u16* Vt = (u16*)(ws + 31723520);           // 8 MB  [bn][d][q]

  prep<<<913, 256, 0, stream>>>(x, Wq, P, xb, Wt, Pb);
  qkv_gemm<<<768, 256, 0, stream>>>(xb, Wt, bq, Qh, Kh, Vt);
  rel_attn<<<512, 512, 0, stream>>>(Qh, Kh, Vt, Pb, rr, rw, out);
}